// Round 1
// baseline (745.215 us; speedup 1.0000x reference)
//
#include <hip/hip_runtime.h>
#include <math.h>

#define B_ 16
#define S_ 6
#define E_ 256
#define NH_ 8
#define HD_ 32
#define HW_ 4096            // 64*64
#define ROWS_ (B_*S_*E_)    // 24576
#define SE_ (S_*E_)         // 1536
#define CROSS_N_ ((size_t)ROWS_*HW_)  // 100663296
#define TRB_ 64             // 4 matrices * 16 (4x4) tiles of 64x64

typedef float f4_t __attribute__((ext_vector_type(4)));

// ---------------- Kernel 1: spatial mean + temporal pos, fused weight transpose ----------------
// blocks [0, ROWS_): one block per (b,s,e) row of 4096 contiguous floats
// blocks [ROWS_, ROWS_+64): transpose Wq/Wk/Wv/Wo into WT (WT[i*E+e] = W[e*E+i])
__global__ __launch_bounds__(256) void pool_tr_kernel(
    const float* __restrict__ ff, const float* __restrict__ tpos,
    float* __restrict__ g,
    const float* __restrict__ Wq, const float* __restrict__ Wk,
    const float* __restrict__ Wv, const float* __restrict__ Wo,
    float* __restrict__ WT)
{
    if (blockIdx.x < ROWS_) {
        const int row = blockIdx.x;
        const f4_t* p = (const f4_t*)(ff + (size_t)row * HW_);
        float sum = 0.f;
        #pragma unroll
        for (int i = 0; i < 4; ++i) {
            f4_t v = p[threadIdx.x + i * 256];
            sum += v.x + v.y + v.z + v.w;
        }
        #pragma unroll
        for (int off = 32; off > 0; off >>= 1)
            sum += __shfl_down(sum, off, 64);
        __shared__ float part[4];
        if ((threadIdx.x & 63) == 0) part[threadIdx.x >> 6] = sum;
        __syncthreads();
        if (threadIdx.x == 0) {
            float tot = part[0] + part[1] + part[2] + part[3];
            g[row] = tot * (1.0f / HW_) + tpos[row % SE_];
        }
    } else {
        __shared__ float tile[64][65];           // +1 pad: conflict-free transpose
        const int tb = blockIdx.x - ROWS_;       // 0..63
        const int m  = tb >> 4;                  // matrix: 0=q 1=k 2=v 3=o
        const int t  = tb & 15;
        const int tr = t >> 2, tc = t & 3;       // 4x4 tiles of 64x64
        const float* W = (m == 0) ? Wq : (m == 1) ? Wk : (m == 2) ? Wv : Wo;
        float* out = WT + (size_t)m * E_ * E_;
        const int c  = threadIdx.x & 63;
        const int r0 = threadIdx.x >> 6;
        #pragma unroll
        for (int k = 0; k < 16; ++k) {
            int r = k * 4 + r0;
            tile[r][c] = W[(size_t)(tr * 64 + r) * E_ + tc * 64 + c];  // coalesced read
        }
        __syncthreads();
        #pragma unroll
        for (int k = 0; k < 16; ++k) {
            int r = k * 4 + r0;
            out[(size_t)(tc * 64 + r) * E_ + tr * 64 + c] = tile[c][r]; // coalesced write
        }
    }
}

// ---------------- Kernel 2: tiny multi-head attention ----------------
// one block per batch element; 256 threads (thread = embed channel e)
// projections now read TRANSPOSED weights -> coalesced (lane stride 4B, not 1KB)
__global__ __launch_bounds__(256) void attn_kernel(
    const float* __restrict__ g, const float* __restrict__ WT,
    const float* __restrict__ bq, const float* __restrict__ bk,
    const float* __restrict__ bv, const float* __restrict__ bo,
    float* __restrict__ out_g, float* __restrict__ attn_out)
{
    __shared__ float sg[S_][E_], sq[S_][E_], sk[S_][E_], sv[S_][E_], satd[S_][E_];
    __shared__ float satt[NH_][S_][S_];
    const int b = blockIdx.x;
    const int e = threadIdx.x;
    const float* WqT = WT;
    const float* WkT = WT + E_ * E_;
    const float* WvT = WT + 2 * E_ * E_;
    const float* WoT = WT + 3 * E_ * E_;

    #pragma unroll
    for (int s = 0; s < S_; ++s)
        sg[s][e] = g[(size_t)b * SE_ + s * E_ + e];
    __syncthreads();

    // q,k,v projections: i outer (coalesced WT loads), 18 register accumulators
    {
        float aq[S_], ak[S_], av[S_];
        #pragma unroll
        for (int s = 0; s < S_; ++s) { aq[s] = bq[e]; ak[s] = bk[e]; av[s] = bv[e]; }
        #pragma unroll 4
        for (int i = 0; i < E_; ++i) {
            float wq = WqT[i * E_ + e];
            float wk = WkT[i * E_ + e];
            float wv = WvT[i * E_ + e];
            #pragma unroll
            for (int s = 0; s < S_; ++s) {
                float gv = sg[s][i];            // LDS broadcast (same addr all lanes)
                aq[s] = fmaf(gv, wq, aq[s]);
                ak[s] = fmaf(gv, wk, ak[s]);
                av[s] = fmaf(gv, wv, av[s]);
            }
        }
        #pragma unroll
        for (int s = 0; s < S_; ++s) {
            sq[s][e] = aq[s]; sk[s][e] = ak[s]; sv[s][e] = av[s];
        }
    }
    __syncthreads();

    // scores with causal mask (288 = 8*6*6 items)
    const float inv_scale = rsqrtf((float)HD_);
    for (int idx = e; idx < NH_ * S_ * S_; idx += 256) {
        int h = idx / (S_ * S_);
        int r = idx % (S_ * S_);
        int s = r / S_, t = r % S_;
        float sc = -INFINITY;
        if (t <= s) {
            sc = 0.f;
            #pragma unroll
            for (int d = 0; d < HD_; ++d)
                sc = fmaf(sq[s][h * HD_ + d], sk[t][h * HD_ + d], sc);
            sc *= inv_scale;
        }
        satt[h][s][t] = sc;
    }
    __syncthreads();

    // row softmax: 48 rows; fully unrolled + predicated (no scratch array)
    if (e < NH_ * S_) {
        int h = e / S_, s = e % S_;
        float m = -INFINITY;
        #pragma unroll
        for (int t = 0; t < S_; ++t)
            if (t <= s) m = fmaxf(m, satt[h][s][t]);
        float ex[S_], sum = 0.f;
        #pragma unroll
        for (int t = 0; t < S_; ++t) {
            ex[t] = (t <= s) ? expf(satt[h][s][t] - m) : 0.0f;
            sum += ex[t];
        }
        float inv = 1.0f / sum;
        #pragma unroll
        for (int t = 0; t < S_; ++t)
            satt[h][s][t] = ex[t] * inv;
    }
    __syncthreads();

    // attended[s][e] = sum_t attn[h][s][t] * v[t][e],  h = e>>5
    {
        const int h = e >> 5;
        #pragma unroll
        for (int s = 0; s < S_; ++s) {
            float a = 0.f;
            #pragma unroll
            for (int t = 0; t < S_; ++t)
                if (t <= s) a = fmaf(satt[h][s][t], sv[t][e], a);
            satd[s][e] = a;
        }
    }
    __syncthreads();

    // output projection, i outer with coalesced WoT loads
    {
        float ao[S_];
        #pragma unroll
        for (int s = 0; s < S_; ++s) ao[s] = bo[e];
        #pragma unroll 4
        for (int i = 0; i < E_; ++i) {
            float wo = WoT[i * E_ + e];
            #pragma unroll
            for (int s = 0; s < S_; ++s)
                ao[s] = fmaf(satd[s][i], wo, ao[s]);
        }
        #pragma unroll
        for (int s = 0; s < S_; ++s)
            out_g[(size_t)b * SE_ + s * E_ + e] = ao[s];
    }

    // emit attn tuple output [B, NH, S, S]
    for (int idx = e; idx < NH_ * S_ * S_; idx += 256) {
        int h = idx / (S_ * S_);
        int r = idx % (S_ * S_);
        attn_out[(size_t)b * (NH_ * S_ * S_) + idx] = satt[h][r / S_][r % S_];
    }
}

// ---------------- Kernel 3: broadcast add ----------------
// REVERSE row order: tail of ff is still L3-resident from pool_kernel (403MB vs 256MB L3)
// non-temporal load/store: don't let the cross write stream evict unread ff
__global__ __launch_bounds__(256) void add_kernel(
    const float* __restrict__ ff, const float* __restrict__ out_g,
    float* __restrict__ cross)
{
    const int row = (ROWS_ - 1) - blockIdx.x;
    const float add = out_g[row];      // wave-uniform -> scalar load
    const f4_t* p = (const f4_t*)(ff + (size_t)row * HW_);
    f4_t* q = (f4_t*)(cross + (size_t)row * HW_);
    #pragma unroll
    for (int i = 0; i < 4; ++i) {
        f4_t v = __builtin_nontemporal_load(&p[threadIdx.x + i * 256]);
        v += add;
        __builtin_nontemporal_store(v, &q[threadIdx.x + i * 256]);
    }
}

extern "C" void kernel_launch(void* const* d_in, const int* in_sizes, int n_in,
                              void* d_out, int out_size, void* d_ws, size_t ws_size,
                              hipStream_t stream) {
    const float* ff   = (const float*)d_in[0];
    const float* Wq   = (const float*)d_in[1];
    const float* bq   = (const float*)d_in[2];
    const float* Wk   = (const float*)d_in[3];
    const float* bk   = (const float*)d_in[4];
    const float* Wv   = (const float*)d_in[5];
    const float* bv   = (const float*)d_in[6];
    const float* Wo   = (const float*)d_in[7];
    const float* bo   = (const float*)d_in[8];
    const float* tpos = (const float*)d_in[9];

    float* out   = (float*)d_out;
    float* g     = (float*)d_ws;        // 24576 floats
    float* out_g = g + ROWS_;           // 24576 floats
    float* WT    = out_g + ROWS_;       // 4*256*256 = 262144 floats (~1.2MB ws total)

    float* cross    = out;              // 100663296 floats
    float* attn_out = out + CROSS_N_;   // 4608 floats

    pool_tr_kernel<<<ROWS_ + TRB_, 256, 0, stream>>>(ff, tpos, g, Wq, Wk, Wv, Wo, WT);
    attn_kernel<<<B_, 256, 0, stream>>>(g, WT, bq, bk, bv, bo, out_g, attn_out);
    add_kernel<<<ROWS_, 256, 0, stream>>>(ff, out_g, cross);
}

// Round 4
// 732.779 us; speedup vs baseline: 1.0170x; 1.0170x over previous
//
#include <hip/hip_runtime.h>
#include <math.h>

#define B_ 16
#define S_ 6
#define E_ 256
#define NH_ 8
#define HD_ 32
#define HW_ 4096            // 64*64
#define ROWS_ (B_*S_*E_)    // 24576
#define BS_ (B_*S_)         // 96
#define SE_ (S_*E_)         // 1536
#define CROSS_N_ ((size_t)ROWS_*HW_)  // 100663296
#define TRB_ 64             // 4 matrices * 16 (4x4) tiles of 64x64

typedef float f4_t __attribute__((ext_vector_type(4)));

// ---------------- Kernel 1: spatial mean + temporal pos, fused weight transpose ----------------
// blocks [0, ROWS_): one block per (b,s,e) row of 4096 contiguous floats
// blocks [ROWS_, ROWS_+64): transpose Wq/Wk/Wv/Wo into WT (WT[i*E+e] = W[e*E+i])
__global__ __launch_bounds__(256) void pool_tr_kernel(
    const float* __restrict__ ff, const float* __restrict__ tpos,
    float* __restrict__ g,
    const float* __restrict__ Wq, const float* __restrict__ Wk,
    const float* __restrict__ Wv, const float* __restrict__ Wo,
    float* __restrict__ WT)
{
    if (blockIdx.x < ROWS_) {
        const int row = blockIdx.x;
        const f4_t* p = (const f4_t*)(ff + (size_t)row * HW_);
        float sum = 0.f;
        #pragma unroll
        for (int i = 0; i < 4; ++i) {
            f4_t v = p[threadIdx.x + i * 256];
            sum += v.x + v.y + v.z + v.w;
        }
        #pragma unroll
        for (int off = 32; off > 0; off >>= 1)
            sum += __shfl_down(sum, off, 64);
        __shared__ float part[4];
        if ((threadIdx.x & 63) == 0) part[threadIdx.x >> 6] = sum;
        __syncthreads();
        if (threadIdx.x == 0) {
            float tot = part[0] + part[1] + part[2] + part[3];
            g[row] = tot * (1.0f / HW_) + tpos[row % SE_];
        }
    } else {
        __shared__ float tile[64][65];           // +1 pad: conflict-free transpose
        const int tb = blockIdx.x - ROWS_;       // 0..63
        const int m  = tb >> 4;                  // matrix: 0=q 1=k 2=v 3=o
        const int t  = tb & 15;
        const int tr = t >> 2, tc = t & 3;       // 4x4 tiles of 64x64
        const float* W = (m == 0) ? Wq : (m == 1) ? Wk : (m == 2) ? Wv : Wo;
        float* out = WT + (size_t)m * E_ * E_;
        const int c  = threadIdx.x & 63;
        const int r0 = threadIdx.x >> 6;
        #pragma unroll
        for (int k = 0; k < 16; ++k) {
            int r = k * 4 + r0;
            tile[r][c] = W[(size_t)(tr * 64 + r) * E_ + tc * 64 + c];  // coalesced read
        }
        __syncthreads();
        #pragma unroll
        for (int k = 0; k < 16; ++k) {
            int r = k * 4 + r0;
            out[(size_t)(tc * 64 + r) * E_ + tr * 64 + c] = tile[c][r]; // coalesced write
        }
    }
}

// ---------------- Kernel 2a: q,k,v projection ----------------
// one block per (b,s); thread = output channel e; WT reads coalesced.
__global__ __launch_bounds__(256) void qkv_kernel(
    const float* __restrict__ g, const float* __restrict__ WT,
    const float* __restrict__ bq, const float* __restrict__ bk,
    const float* __restrict__ bv,
    float* __restrict__ qws, float* __restrict__ kws, float* __restrict__ vws)
{
    __shared__ float sg[E_];
    const int bs = blockIdx.x;               // b*S_ + s
    const int e  = threadIdx.x;
    const float* WqT = WT;
    const float* WkT = WT + E_ * E_;
    const float* WvT = WT + 2 * E_ * E_;

    sg[e] = g[(size_t)bs * E_ + e];
    __syncthreads();

    float aq = bq[e], ak = bk[e], av = bv[e];
    #pragma unroll 8
    for (int i = 0; i < E_; ++i) {
        float gv = sg[i];                    // LDS broadcast
        aq = fmaf(gv, WqT[i * E_ + e], aq);
        ak = fmaf(gv, WkT[i * E_ + e], ak);
        av = fmaf(gv, WvT[i * E_ + e], av);
    }
    qws[(size_t)bs * E_ + e] = aq;
    kws[(size_t)bs * E_ + e] = ak;
    vws[(size_t)bs * E_ + e] = av;
}

// ---------------- Kernel 2b: attention core (scores, softmax, PV) ----------------
// one block per batch element b; 256 threads
__global__ __launch_bounds__(256) void core_kernel(
    const float* __restrict__ qws, const float* __restrict__ kws,
    const float* __restrict__ vws,
    float* __restrict__ satd_ws, float* __restrict__ attn_out)
{
    __shared__ float sq[S_][E_], sk[S_][E_], sv[S_][E_];
    __shared__ float satt[NH_][S_][S_];
    const int b = blockIdx.x;
    const int e = threadIdx.x;

    #pragma unroll
    for (int s = 0; s < S_; ++s) {
        sq[s][e] = qws[(size_t)b * SE_ + s * E_ + e];
        sk[s][e] = kws[(size_t)b * SE_ + s * E_ + e];
        sv[s][e] = vws[(size_t)b * SE_ + s * E_ + e];
    }
    __syncthreads();

    // scores with causal mask (288 = 8*6*6 items)
    const float inv_scale = rsqrtf((float)HD_);
    for (int idx = e; idx < NH_ * S_ * S_; idx += 256) {
        int h = idx / (S_ * S_);
        int r = idx % (S_ * S_);
        int s = r / S_, t = r % S_;
        float sc = -INFINITY;
        if (t <= s) {
            sc = 0.f;
            #pragma unroll
            for (int d = 0; d < HD_; ++d)
                sc = fmaf(sq[s][h * HD_ + d], sk[t][h * HD_ + d], sc);
            sc *= inv_scale;
        }
        satt[h][s][t] = sc;
    }
    __syncthreads();

    // row softmax: 48 rows; fully unrolled + predicated
    if (e < NH_ * S_) {
        int h = e / S_, s = e % S_;
        float m = -INFINITY;
        #pragma unroll
        for (int t = 0; t < S_; ++t)
            if (t <= s) m = fmaxf(m, satt[h][s][t]);
        float ex[S_], sum = 0.f;
        #pragma unroll
        for (int t = 0; t < S_; ++t) {
            ex[t] = (t <= s) ? expf(satt[h][s][t] - m) : 0.0f;
            sum += ex[t];
        }
        float inv = 1.0f / sum;
        #pragma unroll
        for (int t = 0; t < S_; ++t)
            satt[h][s][t] = ex[t] * inv;
    }
    __syncthreads();

    // attended[s][e] = sum_t attn[h][s][t] * v[t][e],  h = e>>5
    {
        const int h = e >> 5;
        #pragma unroll
        for (int s = 0; s < S_; ++s) {
            float a = 0.f;
            #pragma unroll
            for (int t = 0; t < S_; ++t)
                if (t <= s) a = fmaf(satt[h][s][t], sv[t][e], a);
            satd_ws[(size_t)b * SE_ + s * E_ + e] = a;
        }
    }

    // emit attn tuple output [B, NH, S, S]
    for (int idx = e; idx < NH_ * S_ * S_; idx += 256) {
        int h = idx / (S_ * S_);
        int r = idx % (S_ * S_);
        attn_out[(size_t)b * (NH_ * S_ * S_) + idx] = satt[h][r / S_][r % S_];
    }
}

// ---------------- Kernel 2c: output projection ----------------
// one block per (b,s); thread = output channel e
__global__ __launch_bounds__(256) void outproj_kernel(
    const float* __restrict__ satd_ws, const float* __restrict__ WT,
    const float* __restrict__ bo, float* __restrict__ out_g)
{
    __shared__ float sa[E_];
    const int bs = blockIdx.x;
    const int e  = threadIdx.x;
    const float* WoT = WT + 3 * E_ * E_;

    sa[e] = satd_ws[(size_t)bs * E_ + e];
    __syncthreads();

    float ao = bo[e];
    #pragma unroll 8
    for (int i = 0; i < E_; ++i)
        ao = fmaf(sa[i], WoT[i * E_ + e], ao);
    out_g[(size_t)bs * E_ + e] = ao;
}

// ---------------- Kernel 3: broadcast add ----------------
// REVERSE row order: tail of ff is still L3-resident from pool_kernel.
// CACHED loads (so the L3 leftovers actually hit) + non-temporal STORES
// (the cross stream is write-once; don't let it evict unread ff).
__global__ __launch_bounds__(256) void add_kernel(
    const float* __restrict__ ff, const float* __restrict__ out_g,
    float* __restrict__ cross)
{
    const int row = (ROWS_ - 1) - blockIdx.x;
    const float add = out_g[row];      // wave-uniform -> scalar load
    const f4_t* p = (const f4_t*)(ff + (size_t)row * HW_);
    f4_t* q = (f4_t*)(cross + (size_t)row * HW_);
    #pragma unroll
    for (int i = 0; i < 4; ++i) {
        f4_t v = p[threadIdx.x + i * 256];   // cached: harvest L3 tail
        v += add;
        __builtin_nontemporal_store(v, &q[threadIdx.x + i * 256]);
    }
}

extern "C" void kernel_launch(void* const* d_in, const int* in_sizes, int n_in,
                              void* d_out, int out_size, void* d_ws, size_t ws_size,
                              hipStream_t stream) {
    const float* ff   = (const float*)d_in[0];
    const float* Wq   = (const float*)d_in[1];
    const float* bq   = (const float*)d_in[2];
    const float* Wk   = (const float*)d_in[3];
    const float* bk   = (const float*)d_in[4];
    const float* Wv   = (const float*)d_in[5];
    const float* bv   = (const float*)d_in[6];
    const float* Wo   = (const float*)d_in[7];
    const float* bo   = (const float*)d_in[8];
    const float* tpos = (const float*)d_in[9];

    float* out   = (float*)d_out;
    float* g     = (float*)d_ws;        // 24576
    float* out_g = g + ROWS_;           // 24576
    float* WT    = out_g + ROWS_;       // 262144
    float* qws   = WT + 4 * E_ * E_;    // 24576
    float* kws   = qws + ROWS_;         // 24576
    float* vws   = kws + ROWS_;         // 24576
    float* satd  = vws + ROWS_;         // 24576  (total ws ~1.64 MB)

    float* cross    = out;              // 100663296 floats
    float* attn_out = out + CROSS_N_;   // 4608 floats

    pool_tr_kernel<<<ROWS_ + TRB_, 256, 0, stream>>>(ff, tpos, g, Wq, Wk, Wv, Wo, WT);
    qkv_kernel<<<BS_, 256, 0, stream>>>(g, WT, bq, bk, bv, qws, kws, vws);
    core_kernel<<<B_, 256, 0, stream>>>(qws, kws, vws, satd, attn_out);
    outproj_kernel<<<BS_, 256, 0, stream>>>(satd, WT, bo, out_g);
    add_kernel<<<ROWS_, 256, 0, stream>>>(ff, out_g, cross);
}